// Round 7
// baseline (185.004 us; speedup 1.0000x reference)
//
#include <hip/hip_runtime.h>
#include <hip/hip_bf16.h>

typedef __attribute__((ext_vector_type(8))) short short8;     // 8 bf16 (MFMA A/B frag, K=32)
typedef __attribute__((ext_vector_type(4))) float float4v;    // MFMA C/D frag

// ---------------------------------------------------------------------------
// prep_all: all input prep in ONE launch.
//   blocks [0,4096):     x fp32 -> xb bf16 (float4 vectorized)
//   blocks [4096,4352):  RoPE table tab[s][p] = (cos,sin), 512 KB, L2-resident
//   blocks [4352,7424):  Wqkv (1024x3072) -> WqkvT (3072x1024) bf16 transpose
//   blocks [7424,8448):  Wout (1024x1024) -> WoutT transpose
// ---------------------------------------------------------------------------
__global__ __launch_bounds__(256) void prep_all(
    const float* __restrict__ x, __hip_bfloat16* __restrict__ xb,
    float2* __restrict__ tab,
    const float* __restrict__ Wqkv, const float* __restrict__ Wout,
    __hip_bfloat16* __restrict__ WqkvT, __hip_bfloat16* __restrict__ WoutT) {
  __shared__ __hip_bfloat16 tile[32][33];
  const int id = blockIdx.x;
  if (id < 4096) {
    const int i = id * 256 + threadIdx.x;
    const float4 v = *(const float4*)(x + (size_t)i * 4);
    __hip_bfloat16 o[4];
    o[0] = __float2bfloat16(v.x); o[1] = __float2bfloat16(v.y);
    o[2] = __float2bfloat16(v.z); o[3] = __float2bfloat16(v.w);
    *(uint2*)(xb + (size_t)i * 4) = *(const uint2*)o;
    return;
  }
  if (id < 4352) {
    const int i = (id - 4096) * 256 + threadIdx.x;   // 65536
    const int s = i >> 5, p = i & 31;
    const float freq = powf(10000.f, -(float)(p * 2) / 64.f);
    float sn, cs;
    sincosf((float)s * freq, &sn, &cs);
    tab[i] = make_float2(cs, sn);
    return;
  }
  const float* in;
  __hip_bfloat16* out;
  int C, bx, by;
  if (id < 7424) {
    const int lid = id - 4352;
    in = Wqkv; out = WqkvT; C = 3072; bx = lid % 96; by = lid / 96;
  } else {
    const int lid = id - 7424;
    in = Wout; out = WoutT; C = 1024; bx = lid & 31; by = lid >> 5;
  }
  const int R = 1024;
  const int c0 = bx * 32, r0 = by * 32;
  const int tx = threadIdx.x & 31, ty = threadIdx.x >> 5;  // ty 0..7
  #pragma unroll
  for (int i = ty; i < 32; i += 8)
    tile[i][tx] = __float2bfloat16(in[(size_t)(r0 + i) * C + (c0 + tx)]);
  __syncthreads();
  #pragma unroll
  for (int i = ty; i < 32; i += 8)
    out[(size_t)(c0 + i) * R + (r0 + tx)] = tile[tx][i];
}

// ---------------------------------------------------------------------------
// gemm_bt: used only for gemm2 now (r6/r12 measured-optimum 2-barrier form).
// ---------------------------------------------------------------------------
template <typename OutT, int BM, int BN>
__global__ __launch_bounds__(256) void gemm_bt(
    const __hip_bfloat16* __restrict__ A,
    const __hip_bfloat16* __restrict__ Bt,
    OutT* __restrict__ C,
    int M, int N, int K) {
  __shared__ __hip_bfloat16 lA[BM][64];
  __shared__ __hip_bfloat16 lB[BN][64];
  constexpr int NI = BM / 32, NJ = BN / 32;
  const int t = threadIdx.x;
  const int lane = t & 63, wave = t >> 6;
  const int quad = lane >> 4, ln = lane & 15;
  const int m0 = blockIdx.y * BM, n0 = blockIdx.x * BN;
  const int wm = (wave >> 1) * (BM / 2), wn = (wave & 1) * (BN / 2);
  const int srow = lane >> 3;
  const int schunk = ((lane & 7) ^ srow) * 8;

  float4v acc[NI][NJ];
  #pragma unroll
  for (int i = 0; i < NI; ++i)
    #pragma unroll
    for (int j = 0; j < NJ; ++j)
      acc[i][j] = (float4v){0.f, 0.f, 0.f, 0.f};

  for (int kt = 0; kt < K; kt += 64) {
    __syncthreads();
    #pragma unroll
    for (int g = 0; g < BM / 32; ++g) {
      const int rbase = wave * (BM / 4) + g * 8;
      __builtin_amdgcn_global_load_lds(
          (const __attribute__((address_space(1))) void*)
              (A + (size_t)(m0 + rbase + srow) * K + kt + schunk),
          (__attribute__((address_space(3))) void*)&lA[rbase][0], 16, 0, 0);
    }
    #pragma unroll
    for (int g = 0; g < BN / 32; ++g) {
      const int rbase = wave * (BN / 4) + g * 8;
      __builtin_amdgcn_global_load_lds(
          (const __attribute__((address_space(1))) void*)
              (Bt + (size_t)(n0 + rbase + srow) * K + kt + schunk),
          (__attribute__((address_space(3))) void*)&lB[rbase][0], 16, 0, 0);
    }
    __syncthreads();
    #pragma unroll
    for (int step = 0; step < 2; ++step) {
      short8 af[NI], bf[NJ];
      #pragma unroll
      for (int i = 0; i < NI; ++i)
        af[i] = *(const short8*)&lA[wm + i * 16 + ln][((step * 4 + quad) ^ (ln & 7)) * 8];
      #pragma unroll
      for (int j = 0; j < NJ; ++j)
        bf[j] = *(const short8*)&lB[wn + j * 16 + ln][((step * 4 + quad) ^ (ln & 7)) * 8];
      #pragma unroll
      for (int i = 0; i < NI; ++i)
        #pragma unroll
        for (int j = 0; j < NJ; ++j)
          acc[i][j] = __builtin_amdgcn_mfma_f32_16x16x32_bf16(af[i], bf[j], acc[i][j], 0, 0, 0);
    }
  }
  #pragma unroll
  for (int i = 0; i < NI; ++i)
    #pragma unroll
    for (int j = 0; j < NJ; ++j)
      #pragma unroll
      for (int r = 0; r < 4; ++r) {
        const int row = m0 + wm + i * 16 + quad * 4 + r;
        const int col = n0 + wn + j * 16 + ln;
        if constexpr (__is_same(OutT, float))
          C[(size_t)row * N + col] = acc[i][j][r];
        else
          C[(size_t)row * N + col] = __float2bfloat16(acc[i][j][r]);
      }
}

// ---------------------------------------------------------------------------
// gemm1_pipe (r22): 256x256 tile, BK=32, 4-buffer LDS ring, counted vmcnt,
// raw s_barrier — ONE barrier per K-tile, vmcnt never drained to 0 in-loop.
// Race-freedom argument:
//   iter t: vmcnt(8) -> my 4 oldest (tile t) landed; s_barrier -> ALL waves'
//   tile-t slices landed AND all waves' tile t-1 reads (prev iter, before
//   this barrier) done; STAGE(t+3) overwrites buf[(t-1)&3] -- separated from
//   t-1's readers by this barrier. Reads of tile t complete (consumed by
//   MFMA) before this wave reaches iter t+1's barrier; overwrite of tile t's
//   buf happens at iter t+4's stage, behind iter t+4's barrier.
// Ordering pinned: "memory"-clobbered vmcnt asm (gload_lds writes memory ->
// cannot cross), sched_barrier(0) around s_barrier.
// Geometry: 512 thr = 8 waves (2M x 4N), per-wave C = 128x64 (acc[8][4]),
// 12 ds_read_b128 : 32 MFMA per tile (0.375 = m201's proven ratio).
// LDS = 2*(4*256*32*2B) = 128 KiB -> 1 block/CU; grid 12x16=192 balanced.
// Swizzle: storage chunk s of row holds global chunk s^((row>>1)&3) ->
// frag reads are 2-lane/bank (free, m136); staging dest stays lane-linear.
// Tail: peel t=NT-2 (vmcnt(4)) and t=NT-1 (vmcnt(0)).
// ---------------------------------------------------------------------------
__global__ __launch_bounds__(512, 2) void gemm1_pipe(
    const __hip_bfloat16* __restrict__ A,     // xb    4096x1024
    const __hip_bfloat16* __restrict__ Bt,    // WqkvT 3072x1024
    __hip_bfloat16* __restrict__ C) {         // qkv   4096x3072
  constexpr int KD = 1024, NN = 3072, NT = KD / 32;   // 32 K-tiles
  __shared__ __hip_bfloat16 lA[4][256][32];
  __shared__ __hip_bfloat16 lB[4][256][32];
  const int t = threadIdx.x;
  const int lane = t & 63, w = t >> 6;
  const int quad = lane >> 4, ln = lane & 15;
  const int m0 = blockIdx.y * 256, n0 = blockIdx.x * 256;
  const int wm = (w >> 2) * 128, wn = (w & 3) * 64;
  // staging map (tile-invariant): thread covers rows {srow, 128+srow}
  const int srow = t >> 2;                 // 0..127
  const int dch  = t & 3;                  // dest 16B chunk
  const int gch  = dch ^ ((t >> 3) & 3);   // global 16B chunk (pre-swizzled)
  // frag-read chunk: global chunk 'quad' lives at storage chunk quad^((ln>>1)&3)
  const int rch = (quad ^ ((ln >> 1) & 3)) * 8;

  float4v acc[8][4];
  #pragma unroll
  for (int mq = 0; mq < 8; ++mq)
    #pragma unroll
    for (int nq = 0; nq < 4; ++nq)
      acc[mq][nq] = (float4v){0.f, 0.f, 0.f, 0.f};

  auto STAGE = [&](int tile) {
    const int buf = tile & 3;
    #pragma unroll
    for (int g = 0; g < 2; ++g) {
      const int row = g * 128 + srow;
      __builtin_amdgcn_global_load_lds(
          (const __attribute__((address_space(1))) void*)
              (A + (size_t)(m0 + row) * KD + tile * 32 + gch * 8),
          (__attribute__((address_space(3))) void*)&lA[buf][row][dch * 8], 16, 0, 0);
    }
    #pragma unroll
    for (int g = 0; g < 2; ++g) {
      const int row = g * 128 + srow;
      __builtin_amdgcn_global_load_lds(
          (const __attribute__((address_space(1))) void*)
              (Bt + (size_t)(n0 + row) * KD + tile * 32 + gch * 8),
          (__attribute__((address_space(3))) void*)&lB[buf][row][dch * 8], 16, 0, 0);
    }
  };

  auto COMPUTE = [&](int tile) {
    const int buf = tile & 3;
    short8 af[8], bf[4];
    #pragma unroll
    for (int mq = 0; mq < 8; ++mq)
      af[mq] = *(const short8*)&lA[buf][wm + mq * 16 + ln][rch];
    #pragma unroll
    for (int nq = 0; nq < 4; ++nq)
      bf[nq] = *(const short8*)&lB[buf][wn + nq * 16 + ln][rch];
    __builtin_amdgcn_s_setprio(1);
    #pragma unroll
    for (int mq = 0; mq < 8; ++mq)
      #pragma unroll
      for (int nq = 0; nq < 4; ++nq)
        acc[mq][nq] = __builtin_amdgcn_mfma_f32_16x16x32_bf16(af[mq], bf[nq], acc[mq][nq], 0, 0, 0);
    __builtin_amdgcn_s_setprio(0);
  };

  STAGE(0); STAGE(1); STAGE(2);            // 12 loads in flight

  for (int tile = 0; tile < NT - 2; ++tile) {
    asm volatile("s_waitcnt vmcnt(8)" ::: "memory");
    __builtin_amdgcn_sched_barrier(0);
    __builtin_amdgcn_s_barrier();
    __builtin_amdgcn_sched_barrier(0);
    if (tile < NT - 3) STAGE(tile + 3);
    COMPUTE(tile);
  }
  asm volatile("s_waitcnt vmcnt(4)" ::: "memory");
  __builtin_amdgcn_sched_barrier(0);
  __builtin_amdgcn_s_barrier();
  __builtin_amdgcn_sched_barrier(0);
  COMPUTE(NT - 2);
  asm volatile("s_waitcnt vmcnt(0)" ::: "memory");
  __builtin_amdgcn_sched_barrier(0);
  __builtin_amdgcn_s_barrier();
  __builtin_amdgcn_sched_barrier(0);
  COMPUTE(NT - 1);

  // Epilogue: C/D layout row = quad*4 + r, col = ln (m89/m91-verified).
  #pragma unroll
  for (int mq = 0; mq < 8; ++mq)
    #pragma unroll
    for (int nq = 0; nq < 4; ++nq)
      #pragma unroll
      for (int r = 0; r < 4; ++r) {
        const int row = m0 + wm + mq * 16 + quad * 4 + r;
        const int col = n0 + wn + nq * 16 + ln;
        C[(size_t)row * NN + col] = __float2bfloat16(acc[mq][nq][r]);
      }
}

// ---------------------------------------------------------------------------
// Fused QKV prep (table-driven, r12 form): rope(Q,K) reshape + V transpose,
// one qkv pass, zero transcendentals. Q scaled by (1/8)*log2(e).
// ---------------------------------------------------------------------------
__global__ __launch_bounds__(256) void qkv_prep(
    const __hip_bfloat16* __restrict__ qkv,
    const float2* __restrict__ tab,
    __hip_bfloat16* __restrict__ Q,
    __hip_bfloat16* __restrict__ K,
    __hip_bfloat16* __restrict__ Vt) {
  __shared__ __hip_bfloat16 tile[64][65];
  const int s0 = blockIdx.x * 64;
  const int bh = blockIdx.y;
  const int h = bh & 15, b = bh >> 4;
  const int t = threadIdx.x;

  const int pr = t & 31, sl = t >> 5;
  const int d0 = pr * 2;
  const float qs = 0.125f * 1.44269504088896340736f;  // (1/8)*log2(e)
  #pragma unroll
  for (int ss = sl; ss < 64; ss += 8) {
    const int s = s0 + ss;
    const float2 cssn = tab[(size_t)s * 32 + pr];
    const float cs = cssn.x, sn = cssn.y;
    const size_t in_base = (size_t)(b * 2048 + s) * 3072;
    const size_t o = ((size_t)bh * 2048 + s) * 64 + d0;

    __hip_bfloat162 q2 = *(const __hip_bfloat162*)&qkv[in_base + h * 64 + d0];
    float x1 = __bfloat162float(q2.x), x2 = __bfloat162float(q2.y);
    __hip_bfloat162 qo;
    qo.x = __float2bfloat16((x1 * cs - x2 * sn) * qs);
    qo.y = __float2bfloat16((x1 * sn + x2 * cs) * qs);
    *(__hip_bfloat162*)&Q[o] = qo;

    __hip_bfloat162 k2 = *(const __hip_bfloat162*)&qkv[in_base + 1024 + h * 64 + d0];
    x1 = __bfloat162float(k2.x); x2 = __bfloat162float(k2.y);
    __hip_bfloat162 ko;
    ko.x = __float2bfloat16(x1 * cs - x2 * sn);
    ko.y = __float2bfloat16(x1 * sn + x2 * cs);
    *(__hip_bfloat162*)&K[o] = ko;
  }

  const int tx = t & 63, ty = t >> 6;  // ty 0..3
  #pragma unroll
  for (int i = ty; i < 64; i += 4)
    tile[i][tx] = qkv[(size_t)(b * 2048 + s0 + i) * 3072 + 2048 + h * 64 + tx];
  __syncthreads();
  #pragma unroll
  for (int i = ty; i < 64; i += 4)
    Vt[((size_t)bh * 64 + i) * 2048 + s0 + tx] = tile[tx][i];
}

// ---------------------------------------------------------------------------
// Flash-style causal attention — r21 form (verified win): swapped-operand QK,
// in-register P via sigma row permutation, V dbuf, ONE barrier/iter.
// ---------------------------------------------------------------------------
__global__ __launch_bounds__(256) void attention(
    const __hip_bfloat16* __restrict__ Q,
    const __hip_bfloat16* __restrict__ K,
    const __hip_bfloat16* __restrict__ Vt,
    __hip_bfloat16* __restrict__ attn) {
  __shared__ __hip_bfloat16 lK[2][64][64];    // [buf][sk][d]  XOR-swizzled, dbuf
  __shared__ __hip_bfloat16 lV[2][64][64];    // [buf][d][sk]  XOR-swizzled, dbuf
  __shared__ __hip_bfloat16 lO[4][16][64];    // per-wave epilogue transpose
  const int t = threadIdx.x;
  const int lane = t & 63, w = t >> 6;
  const int quad = lane >> 4, ln = lane & 15;
  const int id = blockIdx.x;
  const int bh = id & 31;                     // fast index -> XCD spread
  const int j = id >> 5;                      // 0..31
  const int k2 = j >> 3, g = j & 7;
  const int qt = 8 * k2 + ((k2 & 1) ? (7 - g) : g);   // balanced qt perm
  const int q0 = qt * 64;
  const size_t base = (size_t)bh * 2048 * 64;
  const __hip_bfloat16* Qb = Q + base;
  const __hip_bfloat16* Kb = K + base;
  const __hip_bfloat16* Vb = Vt + base;
  const int b = bh >> 4, h = bh & 15;

  const int srow = lane >> 3;
  const int schunk = ((lane & 7) ^ srow) * 8;
  const int rb0 = w * 16;
  // sigma row base: sigma(nt, ln) = sig_base + ((nt&1)<<2) + ((nt>>1)<<5)
  const int sig_base = (ln >> 2) * 8 + (ln & 3);

  // Prologue: stage K[0] + V[0] into buf 0.
  #pragma unroll
  for (int g2 = 0; g2 < 2; ++g2) {
    const int rbase = rb0 + g2 * 8;
    __builtin_amdgcn_global_load_lds(
        (const __attribute__((address_space(1))) void*)
            (Kb + (size_t)(rbase + srow) * 64 + schunk),
        (__attribute__((address_space(3))) void*)&lK[0][rbase][0], 16, 0, 0);
    __builtin_amdgcn_global_load_lds(
        (const __attribute__((address_space(1))) void*)
            (Vb + (size_t)(rbase + srow) * 2048 + schunk),
        (__attribute__((address_space(3))) void*)&lV[0][rbase][0], 16, 0, 0);
  }

  short8 qf[2];
  {
    const size_t qrow = (size_t)(q0 + w * 16 + ln) * 64;
    qf[0] = *(const short8*)(Qb + qrow + quad * 8);
    qf[1] = *(const short8*)(Qb + qrow + 32 + quad * 8);
  }

  float4v acc_o[4];
  #pragma unroll
  for (int dt = 0; dt < 4; ++dt) acc_o[dt] = (float4v){0.f, 0.f, 0.f, 0.f};
  float suml = 0.f;

  for (int kt = 0; kt <= qt; ++kt) {
    const int buf = kt & 1;
    __syncthreads();   // drains K[kt]/V[kt] DMA (issued a full iter ago);
                       // prev iter's buf^1 reads are all before this point

    if (kt < qt) {
      #pragma unroll
      for (int g2 = 0; g2 < 2; ++g2) {
        const int rbase = rb0 + g2 * 8;
        __builtin_amdgcn_global_load_lds(
            (const __attribute__((address_space(1))) void*)
                (Kb + (size_t)((kt + 1) * 64 + rbase + srow) * 64 + schunk),
            (__attribute__((address_space(3))) void*)&lK[buf ^ 1][rbase][0], 16, 0, 0);
        __builtin_amdgcn_global_load_lds(
            (const __attribute__((address_space(1))) void*)
                (Vb + (size_t)(rbase + srow) * 2048 + (kt + 1) * 64 + schunk),
            (__attribute__((address_space(3))) void*)&lV[buf ^ 1][rbase][0], 16, 0, 0);
      }
    }

    // QK^T swapped: s4[nt] lane(quad,ln) reg r = P[sigma(nt,quad*4+r)][q=ln]
    float4v s4[4];
    #pragma unroll
    for (int nt = 0; nt < 4; ++nt) {
      const int krow = sig_base + ((nt & 1) << 2) + ((nt >> 1) << 5);
      const int k7 = krow & 7;
      float4v a = (float4v){0.f, 0.f, 0.f, 0.f};
      #pragma unroll
      for (int step = 0; step < 2; ++step) {
        short8 kf = *(const short8*)&lK[buf][krow][((step * 4 + quad) ^ k7) * 8];
        a = __builtin_amdgcn_mfma_f32_16x16x32_bf16(kf, qf[step], a, 0, 0, 0);
      }
      s4[nt] = a;
    }
    if (kt == qt) {
      const int qr = q0 + w * 16 + ln;
      #pragma unroll
      for (int nt = 0; nt < 4; ++nt)
        #pragma unroll
        for (int r = 0; r < 4; ++r) {
          const int kglob = kt * 64 + quad * 8 + ((nt & 1) << 2) + r + ((nt >> 1) << 5);
          if (kglob > qr) s4[nt][r] = -64.f;
        }
    }
    // exp (bare v_exp_f32) + row-sum contribution
    #pragma unroll
    for (int nt = 0; nt < 4; ++nt)
      #pragma unroll
      for (int r = 0; r < 4; ++r) {
        s4[nt][r] = __builtin_amdgcn_exp2f(s4[nt][r]);
        suml += s4[nt][r];
      }
    // PV: B-frag step s = lane-local pack of s4[2s][0..3], s4[2s+1][0..3]
    #pragma unroll
    for (int s = 0; s < 2; ++s) {
      union { short8 v; short e[8]; } pb;
      #pragma unroll
      for (int i = 0; i < 4; ++i) {
        __hip_bfloat16 b0 = __float2bfloat16(s4[2 * s][i]);
        __hip_bfloat16 b1 = __float2bfloat16(s4[2 * s + 1][i]);
        pb.e[i] = *reinterpret_cast<short*>(&b0);
        pb.e[4 + i] = *reinterpret_cast<short*>(&b1);
      }
      #pragma unroll
      for (int dt = 0; dt < 4; ++dt) {
        short8 vf = *(const short8*)&lV[buf][dt * 16 + ln][((s * 4 + quad) ^ (ln & 7)) * 8];
        acc_o[dt] = __builtin_amdgcn_mfma_f32_16x16x32_bf16(vf, pb.v, acc_o[dt], 0, 0, 0);
      }
    }
  }

  // l[q] = sum over the 4 quads holding q=ln's P-columns
  float l0 = suml + __shfl_xor(suml, 16);
  const float inv = 1.0f / (l0 + __shfl_xor(l0, 32));

  // Epilogue: lane holds O^T[d=dt*16+quad*4+r][q=ln]; transpose via per-wave
  // LDS tile (wave-local, no block barrier) then coalesced 32B stores.
  #pragma unroll
  for (int dt = 0; dt < 4; ++dt)
    #pragma unroll
    for (int r = 0; r < 4; ++r)
      lO[w][ln][dt * 16 + quad * 4 + r] = __float2bfloat16(acc_o[dt][r] * inv);

  const int orow = lane >> 2;           // q' 0..15
  const int od = (lane & 3) * 16;       // d base (16 elems = 32B per lane)
  const uint4 w0 = *(const uint4*)&lO[w][orow][od];
  const uint4 w1 = *(const uint4*)&lO[w][orow][od + 8];
  const size_t rg = (size_t)(b * 2048 + q0 + w * 16 + orow);
  *(uint4*)&attn[rg * 1024 + h * 64 + od] = w0;
  *(uint4*)&attn[rg * 1024 + h * 64 + od + 8] = w1;
}

// ---------------------------------------------------------------------------
extern "C" void kernel_launch(void* const* d_in, const int* in_sizes, int n_in,
                              void* d_out, int out_size, void* d_ws, size_t ws_size,
                              hipStream_t stream) {
  const float* x    = (const float*)d_in[0];  // (2,2048,1024) fp32
  const float* Wqkv = (const float*)d_in[1];  // (1024,3072)   fp32
  const float* Wout = (const float*)d_in[2];  // (1024,1024)   fp32
  float* out = (float*)d_out;                 // (2,2048,1024) fp32

  __hip_bfloat16* ws = (__hip_bfloat16*)d_ws;
  __hip_bfloat16* xb    = ws;                          // 4096*1024
  __hip_bfloat16* WqkvT = xb    + (size_t)4096 * 1024; // 3072*1024
  __hip_bfloat16* WoutT = WqkvT + (size_t)3072 * 1024; // 1024*1024
  __hip_bfloat16* qkv   = WoutT + (size_t)1024 * 1024; // 4096*3072
  __hip_bfloat16* Q     = qkv   + (size_t)4096 * 3072; // 32*2048*64
  __hip_bfloat16* K     = Q     + (size_t)32 * 2048 * 64;
  __hip_bfloat16* Vt    = K     + (size_t)32 * 2048 * 64;
  __hip_bfloat16* attn  = Vt    + (size_t)32 * 2048 * 64;  // dedicated
  float2*         tab   = (float2*)(attn + (size_t)4096 * 1024);  // 2048x32

  prep_all<<<8448, 256, 0, stream>>>(x, xb, tab, Wqkv, Wout, WqkvT, WoutT);
  gemm1_pipe<<<dim3(3072 / 256, 4096 / 256), 512, 0, stream>>>(xb, WqkvT, qkv);
  qkv_prep<<<dim3(32, 32), 256, 0, stream>>>(qkv, tab, Q, K, Vt);
  attention<<<1024, 256, 0, stream>>>(Q, K, Vt, attn);
  gemm_bt<float, 128, 64><<<dim3(1024 / 64, 4096 / 128), 256, 0, stream>>>(attn, WoutT, out, 4096, 1024, 1024);
}

// Round 8
// 179.950 us; speedup vs baseline: 1.0281x; 1.0281x over previous
//
#include <hip/hip_runtime.h>
#include <hip/hip_bf16.h>

typedef __attribute__((ext_vector_type(8))) short short8;     // 8 bf16 (MFMA A/B frag, K=32)
typedef __attribute__((ext_vector_type(4))) float float4v;    // MFMA C/D frag

// ---------------------------------------------------------------------------
// prep_all: all input prep in ONE launch.
//   blocks [0,4096):     x fp32 -> xb bf16 (float4 vectorized)
//   blocks [4096,4352):  RoPE table tab[s][p] = (cos,sin), 512 KB, L2-resident
//   blocks [4352,7424):  Wqkv (1024x3072) -> WqkvT (3072x1024) bf16 transpose
//   blocks [7424,8448):  Wout (1024x1024) -> WoutT transpose
// ---------------------------------------------------------------------------
__global__ __launch_bounds__(256) void prep_all(
    const float* __restrict__ x, __hip_bfloat16* __restrict__ xb,
    float2* __restrict__ tab,
    const float* __restrict__ Wqkv, const float* __restrict__ Wout,
    __hip_bfloat16* __restrict__ WqkvT, __hip_bfloat16* __restrict__ WoutT) {
  __shared__ __hip_bfloat16 tile[32][33];
  const int id = blockIdx.x;
  if (id < 4096) {
    const int i = id * 256 + threadIdx.x;
    const float4 v = *(const float4*)(x + (size_t)i * 4);
    __hip_bfloat16 o[4];
    o[0] = __float2bfloat16(v.x); o[1] = __float2bfloat16(v.y);
    o[2] = __float2bfloat16(v.z); o[3] = __float2bfloat16(v.w);
    *(uint2*)(xb + (size_t)i * 4) = *(const uint2*)o;
    return;
  }
  if (id < 4352) {
    const int i = (id - 4096) * 256 + threadIdx.x;   // 65536
    const int s = i >> 5, p = i & 31;
    const float freq = powf(10000.f, -(float)(p * 2) / 64.f);
    float sn, cs;
    sincosf((float)s * freq, &sn, &cs);
    tab[i] = make_float2(cs, sn);
    return;
  }
  const float* in;
  __hip_bfloat16* out;
  int C, bx, by;
  if (id < 7424) {
    const int lid = id - 4352;
    in = Wqkv; out = WqkvT; C = 3072; bx = lid % 96; by = lid / 96;
  } else {
    const int lid = id - 7424;
    in = Wout; out = WoutT; C = 1024; bx = lid & 31; by = lid >> 5;
  }
  const int R = 1024;
  const int c0 = bx * 32, r0 = by * 32;
  const int tx = threadIdx.x & 31, ty = threadIdx.x >> 5;  // ty 0..7
  #pragma unroll
  for (int i = ty; i < 32; i += 8)
    tile[i][tx] = __float2bfloat16(in[(size_t)(r0 + i) * C + (c0 + tx)]);
  __syncthreads();
  #pragma unroll
  for (int i = ty; i < 32; i += 8)
    out[(size_t)(c0 + i) * R + (r0 + tx)] = tile[tx][i];
}

// ---------------------------------------------------------------------------
// gemm_bt: C (MxN, OutT) = A (MxK, row-major bf16) @ Bt^T  (Bt is NxK bf16)
// r6/r12 measured-optimum 2-barrier structure. r22's 256^2 counted-vmcnt ring
// REVERTED: grid 192 < 256 CUs + 1 block/CU (128K LDS) -> 46us vs 40 here.
// gemm1: <bf16,128,128> (768 blocks); gemm2: <float,128,64> (512 blocks).
// ---------------------------------------------------------------------------
template <typename OutT, int BM, int BN>
__global__ __launch_bounds__(256) void gemm_bt(
    const __hip_bfloat16* __restrict__ A,
    const __hip_bfloat16* __restrict__ Bt,
    OutT* __restrict__ C,
    int M, int N, int K) {
  __shared__ __hip_bfloat16 lA[BM][64];
  __shared__ __hip_bfloat16 lB[BN][64];
  constexpr int NI = BM / 32, NJ = BN / 32;
  const int t = threadIdx.x;
  const int lane = t & 63, wave = t >> 6;
  const int quad = lane >> 4, ln = lane & 15;
  const int m0 = blockIdx.y * BM, n0 = blockIdx.x * BN;
  const int wm = (wave >> 1) * (BM / 2), wn = (wave & 1) * (BN / 2);
  const int srow = lane >> 3;
  const int schunk = ((lane & 7) ^ srow) * 8;

  float4v acc[NI][NJ];
  #pragma unroll
  for (int i = 0; i < NI; ++i)
    #pragma unroll
    for (int j = 0; j < NJ; ++j)
      acc[i][j] = (float4v){0.f, 0.f, 0.f, 0.f};

  for (int kt = 0; kt < K; kt += 64) {
    __syncthreads();
    #pragma unroll
    for (int g = 0; g < BM / 32; ++g) {
      const int rbase = wave * (BM / 4) + g * 8;
      __builtin_amdgcn_global_load_lds(
          (const __attribute__((address_space(1))) void*)
              (A + (size_t)(m0 + rbase + srow) * K + kt + schunk),
          (__attribute__((address_space(3))) void*)&lA[rbase][0], 16, 0, 0);
    }
    #pragma unroll
    for (int g = 0; g < BN / 32; ++g) {
      const int rbase = wave * (BN / 4) + g * 8;
      __builtin_amdgcn_global_load_lds(
          (const __attribute__((address_space(1))) void*)
              (Bt + (size_t)(n0 + rbase + srow) * K + kt + schunk),
          (__attribute__((address_space(3))) void*)&lB[rbase][0], 16, 0, 0);
    }
    __syncthreads();
    #pragma unroll
    for (int step = 0; step < 2; ++step) {
      short8 af[NI], bf[NJ];
      #pragma unroll
      for (int i = 0; i < NI; ++i)
        af[i] = *(const short8*)&lA[wm + i * 16 + ln][((step * 4 + quad) ^ (ln & 7)) * 8];
      #pragma unroll
      for (int j = 0; j < NJ; ++j)
        bf[j] = *(const short8*)&lB[wn + j * 16 + ln][((step * 4 + quad) ^ (ln & 7)) * 8];
      #pragma unroll
      for (int i = 0; i < NI; ++i)
        #pragma unroll
        for (int j = 0; j < NJ; ++j)
          acc[i][j] = __builtin_amdgcn_mfma_f32_16x16x32_bf16(af[i], bf[j], acc[i][j], 0, 0, 0);
    }
  }
  #pragma unroll
  for (int i = 0; i < NI; ++i)
    #pragma unroll
    for (int j = 0; j < NJ; ++j)
      #pragma unroll
      for (int r = 0; r < 4; ++r) {
        const int row = m0 + wm + i * 16 + quad * 4 + r;
        const int col = n0 + wn + j * 16 + ln;
        if constexpr (__is_same(OutT, float))
          C[(size_t)row * N + col] = acc[i][j][r];
        else
          C[(size_t)row * N + col] = __float2bfloat16(acc[i][j][r]);
      }
}

// ---------------------------------------------------------------------------
// Fused QKV prep (table-driven, r12 form): rope(Q,K) reshape + V transpose,
// one qkv pass, zero transcendentals. Q scaled by (1/8)*log2(e).
// ---------------------------------------------------------------------------
__global__ __launch_bounds__(256) void qkv_prep(
    const __hip_bfloat16* __restrict__ qkv,
    const float2* __restrict__ tab,
    __hip_bfloat16* __restrict__ Q,
    __hip_bfloat16* __restrict__ K,
    __hip_bfloat16* __restrict__ Vt) {
  __shared__ __hip_bfloat16 tile[64][65];
  const int s0 = blockIdx.x * 64;
  const int bh = blockIdx.y;
  const int h = bh & 15, b = bh >> 4;
  const int t = threadIdx.x;

  const int pr = t & 31, sl = t >> 5;
  const int d0 = pr * 2;
  const float qs = 0.125f * 1.44269504088896340736f;  // (1/8)*log2(e)
  #pragma unroll
  for (int ss = sl; ss < 64; ss += 8) {
    const int s = s0 + ss;
    const float2 cssn = tab[(size_t)s * 32 + pr];
    const float cs = cssn.x, sn = cssn.y;
    const size_t in_base = (size_t)(b * 2048 + s) * 3072;
    const size_t o = ((size_t)bh * 2048 + s) * 64 + d0;

    __hip_bfloat162 q2 = *(const __hip_bfloat162*)&qkv[in_base + h * 64 + d0];
    float x1 = __bfloat162float(q2.x), x2 = __bfloat162float(q2.y);
    __hip_bfloat162 qo;
    qo.x = __float2bfloat16((x1 * cs - x2 * sn) * qs);
    qo.y = __float2bfloat16((x1 * sn + x2 * cs) * qs);
    *(__hip_bfloat162*)&Q[o] = qo;

    __hip_bfloat162 k2 = *(const __hip_bfloat162*)&qkv[in_base + 1024 + h * 64 + d0];
    x1 = __bfloat162float(k2.x); x2 = __bfloat162float(k2.y);
    __hip_bfloat162 ko;
    ko.x = __float2bfloat16(x1 * cs - x2 * sn);
    ko.y = __float2bfloat16(x1 * sn + x2 * cs);
    *(__hip_bfloat162*)&K[o] = ko;
  }

  const int tx = t & 63, ty = t >> 6;  // ty 0..3
  #pragma unroll
  for (int i = ty; i < 64; i += 4)
    tile[i][tx] = qkv[(size_t)(b * 2048 + s0 + i) * 3072 + 2048 + h * 64 + tx];
  __syncthreads();
  #pragma unroll
  for (int i = ty; i < 64; i += 4)
    Vt[((size_t)bh * 64 + i) * 2048 + s0 + tx] = tile[tx][i];
}

// ---------------------------------------------------------------------------
// Flash-style causal attention — r23: QBLK=128 (8 waves, 512 thr). r21's
// swapped-operand/in-register-P per-wave structure is UNCHANGED; what changes
// is sharing: one K/V stage + one barrier now serves 8 waves (128 q-rows)
// instead of 4 (64) -> staged bytes and per-CU barrier slots halve (66->34
// balanced iters/CU), TLP unchanged (2 blocks/CU x 8 waves = 16 waves/CU,
// same as r21's 4x4). Fully-masked tiles skipped wave-uniformly.
// Balance: v=id>>5 (0..15), u = v<8 ? v : 23-v -> CU pair {v, v+8} has
// u-pair {v, 15-v}: NT sums (2v+2)+(2(15-v)+2) = 34 for every CU.
// LDS: lK 16K + lV 16K + lO 16K = 48K -> 2 blocks/CU resident (cap 3).
// ---------------------------------------------------------------------------
__global__ __launch_bounds__(512) void attention(
    const __hip_bfloat16* __restrict__ Q,
    const __hip_bfloat16* __restrict__ K,
    const __hip_bfloat16* __restrict__ Vt,
    __hip_bfloat16* __restrict__ attn) {
  __shared__ __hip_bfloat16 lK[2][64][64];    // [buf][sk][d]  XOR-swizzled, dbuf
  __shared__ __hip_bfloat16 lV[2][64][64];    // [buf][d][sk]  XOR-swizzled, dbuf
  __shared__ __hip_bfloat16 lO[8][16][64];    // per-wave epilogue transpose
  const int t = threadIdx.x;
  const int lane = t & 63, w = t >> 6;        // w 0..7
  const int quad = lane >> 4, ln = lane & 15;
  const int id = blockIdx.x;
  const int bh = id & 31;                     // fast index -> XCD spread
  const int v = id >> 5;                      // 0..15
  const int u = (v < 8) ? v : 23 - v;         // balanced pair mapping
  const int q0 = u * 128;
  const int NT = 2 * u + 2;                   // 64-row K-tiles
  const int ktmask = 2 * u + (w >> 2);        // wave's diagonal tile
  const size_t base = (size_t)bh * 2048 * 64;
  const __hip_bfloat16* Qb = Q + base;
  const __hip_bfloat16* Kb = K + base;
  const __hip_bfloat16* Vb = Vt + base;
  const int b = bh >> 4, h = bh & 15;

  const int srow = lane >> 3;                 // 0..7
  const int schunk = ((lane & 7) ^ srow) * 8;
  const int krow_st = w * 8 + srow;           // staging row (0..63 over 8 waves)
  // sigma row base: sigma(nt, ln) = sig_base + ((nt&1)<<2) + ((nt>>1)<<5)
  const int sig_base = (ln >> 2) * 8 + (ln & 3);

  // Prologue: stage K[0] + V[0] into buf 0 (1 K + 1 V gload per wave).
  __builtin_amdgcn_global_load_lds(
      (const __attribute__((address_space(1))) void*)
          (Kb + (size_t)krow_st * 64 + schunk),
      (__attribute__((address_space(3))) void*)&lK[0][krow_st & 63][0], 16, 0, 0);
  __builtin_amdgcn_global_load_lds(
      (const __attribute__((address_space(1))) void*)
          (Vb + (size_t)krow_st * 2048 + schunk),
      (__attribute__((address_space(3))) void*)&lV[0][krow_st & 63][0], 16, 0, 0);

  short8 qf[2];
  {
    const size_t qrow = (size_t)(q0 + w * 16 + ln) * 64;
    qf[0] = *(const short8*)(Qb + qrow + quad * 8);
    qf[1] = *(const short8*)(Qb + qrow + 32 + quad * 8);
  }

  float4v acc_o[4];
  #pragma unroll
  for (int dt = 0; dt < 4; ++dt) acc_o[dt] = (float4v){0.f, 0.f, 0.f, 0.f};
  float suml = 0.f;

  for (int kt = 0; kt < NT; ++kt) {
    const int buf = kt & 1;
    __syncthreads();   // drains K[kt]/V[kt] DMA (issued a full iter ago);
                       // prev iter's buf^1 reads all precede this point

    if (kt + 1 < NT) {
      __builtin_amdgcn_global_load_lds(
          (const __attribute__((address_space(1))) void*)
              (Kb + (size_t)((kt + 1) * 64 + krow_st) * 64 + schunk),
          (__attribute__((address_space(3))) void*)&lK[buf ^ 1][krow_st][0], 16, 0, 0);
      __builtin_amdgcn_global_load_lds(
          (const __attribute__((address_space(1))) void*)
              (Vb + (size_t)krow_st * 2048 + (kt + 1) * 64 + schunk),
          (__attribute__((address_space(3))) void*)&lV[buf ^ 1][krow_st][0], 16, 0, 0);
    }

    if (kt <= ktmask) {   // wave-uniform: beyond diagonal the tile is all-masked
      // QK^T swapped: s4[nt] lane(quad,ln) reg r = P[sigma(nt,quad*4+r)][q=ln]
      float4v s4[4];
      #pragma unroll
      for (int nt = 0; nt < 4; ++nt) {
        const int krow = sig_base + ((nt & 1) << 2) + ((nt >> 1) << 5);
        const int k7 = krow & 7;
        float4v a = (float4v){0.f, 0.f, 0.f, 0.f};
        #pragma unroll
        for (int step = 0; step < 2; ++step) {
          short8 kf = *(const short8*)&lK[buf][krow][((step * 4 + quad) ^ k7) * 8];
          a = __builtin_amdgcn_mfma_f32_16x16x32_bf16(kf, qf[step], a, 0, 0, 0);
        }
        s4[nt] = a;
      }
      if (kt == ktmask) {
        const int qr = q0 + w * 16 + ln;
        #pragma unroll
        for (int nt = 0; nt < 4; ++nt)
          #pragma unroll
          for (int r = 0; r < 4; ++r) {
            const int kglob = kt * 64 + quad * 8 + ((nt & 1) << 2) + r + ((nt >> 1) << 5);
            if (kglob > qr) s4[nt][r] = -64.f;
          }
      }
      // exp (bare v_exp_f32) + row-sum contribution
      #pragma unroll
      for (int nt = 0; nt < 4; ++nt)
        #pragma unroll
        for (int r = 0; r < 4; ++r) {
          s4[nt][r] = __builtin_amdgcn_exp2f(s4[nt][r]);
          suml += s4[nt][r];
        }
      // PV: B-frag step s = lane-local pack of s4[2s][0..3], s4[2s+1][0..3]
      #pragma unroll
      for (int s = 0; s < 2; ++s) {
        union { short8 v; short e[8]; } pb;
        #pragma unroll
        for (int i = 0; i < 4; ++i) {
          __hip_bfloat16 b0 = __float2bfloat16(s4[2 * s][i]);
          __hip_bfloat16 b1 = __float2bfloat16(s4[2 * s + 1][i]);
          pb.e[i] = *reinterpret_cast<short*>(&b0);
          pb.e[4 + i] = *reinterpret_cast<short*>(&b1);
        }
        #pragma unroll
        for (int dt = 0; dt < 4; ++dt) {
          short8 vf = *(const short8*)&lV[buf][dt * 16 + ln][((s * 4 + quad) ^ (ln & 7)) * 8];
          acc_o[dt] = __builtin_amdgcn_mfma_f32_16x16x32_bf16(vf, pb.v, acc_o[dt], 0, 0, 0);
        }
      }
    }
  }

  // l[q] = sum over the 4 quads holding q=ln's P-columns
  float l0 = suml + __shfl_xor(suml, 16);
  const float inv = 1.0f / (l0 + __shfl_xor(l0, 32));

  // Epilogue: lane holds O^T[d=dt*16+quad*4+r][q=ln]; transpose via per-wave
  // LDS tile (wave-local, no block barrier) then coalesced 32B stores.
  #pragma unroll
  for (int dt = 0; dt < 4; ++dt)
    #pragma unroll
    for (int r = 0; r < 4; ++r)
      lO[w][ln][dt * 16 + quad * 4 + r] = __float2bfloat16(acc_o[dt][r] * inv);

  const int orow = lane >> 2;           // q' 0..15
  const int od = (lane & 3) * 16;       // d base (16 elems = 32B per lane)
  const uint4 w0 = *(const uint4*)&lO[w][orow][od];
  const uint4 w1 = *(const uint4*)&lO[w][orow][od + 8];
  const size_t rg = (size_t)(b * 2048 + q0 + w * 16 + orow);
  *(uint4*)&attn[rg * 1024 + h * 64 + od] = w0;
  *(uint4*)&attn[rg * 1024 + h * 64 + od + 8] = w1;
}

// ---------------------------------------------------------------------------
extern "C" void kernel_launch(void* const* d_in, const int* in_sizes, int n_in,
                              void* d_out, int out_size, void* d_ws, size_t ws_size,
                              hipStream_t stream) {
  const float* x    = (const float*)d_in[0];  // (2,2048,1024) fp32
  const float* Wqkv = (const float*)d_in[1];  // (1024,3072)   fp32
  const float* Wout = (const float*)d_in[2];  // (1024,1024)   fp32
  float* out = (float*)d_out;                 // (2,2048,1024) fp32

  __hip_bfloat16* ws = (__hip_bfloat16*)d_ws;
  __hip_bfloat16* xb    = ws;                          // 4096*1024
  __hip_bfloat16* WqkvT = xb    + (size_t)4096 * 1024; // 3072*1024
  __hip_bfloat16* WoutT = WqkvT + (size_t)3072 * 1024; // 1024*1024
  __hip_bfloat16* qkv   = WoutT + (size_t)1024 * 1024; // 4096*3072
  __hip_bfloat16* Q     = qkv   + (size_t)4096 * 3072; // 32*2048*64
  __hip_bfloat16* K     = Q     + (size_t)32 * 2048 * 64;
  __hip_bfloat16* Vt    = K     + (size_t)32 * 2048 * 64;
  __hip_bfloat16* attn  = Vt    + (size_t)32 * 2048 * 64;  // dedicated
  float2*         tab   = (float2*)(attn + (size_t)4096 * 1024);  // 2048x32

  prep_all<<<8448, 256, 0, stream>>>(x, xb, tab, Wqkv, Wout, WqkvT, WoutT);
  gemm_bt<__hip_bfloat16, 128, 128><<<dim3(3072 / 128, 4096 / 128), 256, 0, stream>>>(xb, WqkvT, qkv, 4096, 3072, 1024);
  qkv_prep<<<dim3(32, 32), 256, 0, stream>>>(qkv, tab, Q, K, Vt);
  attention<<<512, 512, 0, stream>>>(Q, K, Vt, attn);
  gemm_bt<float, 128, 64><<<dim3(1024 / 64, 4096 / 128), 256, 0, stream>>>(attn, WoutT, out, 4096, 1024, 1024);
}

// Round 9
// 172.125 us; speedup vs baseline: 1.0748x; 1.0455x over previous
//
#include <hip/hip_runtime.h>
#include <hip/hip_bf16.h>

typedef __attribute__((ext_vector_type(8))) short short8;     // 8 bf16 (MFMA A/B frag, K=32)
typedef __attribute__((ext_vector_type(4))) float float4v;    // MFMA C/D frag

// ---------------------------------------------------------------------------
// prep_all: all input prep in ONE launch.
//   blocks [0,4096):     x fp32 -> xb bf16 (float4 vectorized)
//   blocks [4096,4352):  RoPE table tab[s][p] = (cos,sin), 512 KB, L2-resident
//   blocks [4352,7424):  Wqkv (1024x3072) -> WqkvT (3072x1024) bf16 transpose
//   blocks [7424,8448):  Wout (1024x1024) -> WoutT transpose
// ---------------------------------------------------------------------------
__global__ __launch_bounds__(256) void prep_all(
    const float* __restrict__ x, __hip_bfloat16* __restrict__ xb,
    float2* __restrict__ tab,
    const float* __restrict__ Wqkv, const float* __restrict__ Wout,
    __hip_bfloat16* __restrict__ WqkvT, __hip_bfloat16* __restrict__ WoutT) {
  __shared__ __hip_bfloat16 tile[32][33];
  const int id = blockIdx.x;
  if (id < 4096) {
    const int i = id * 256 + threadIdx.x;
    const float4 v = *(const float4*)(x + (size_t)i * 4);
    __hip_bfloat16 o[4];
    o[0] = __float2bfloat16(v.x); o[1] = __float2bfloat16(v.y);
    o[2] = __float2bfloat16(v.z); o[3] = __float2bfloat16(v.w);
    *(uint2*)(xb + (size_t)i * 4) = *(const uint2*)o;
    return;
  }
  if (id < 4352) {
    const int i = (id - 4096) * 256 + threadIdx.x;   // 65536
    const int s = i >> 5, p = i & 31;
    const float freq = powf(10000.f, -(float)(p * 2) / 64.f);
    float sn, cs;
    sincosf((float)s * freq, &sn, &cs);
    tab[i] = make_float2(cs, sn);
    return;
  }
  const float* in;
  __hip_bfloat16* out;
  int C, bx, by;
  if (id < 7424) {
    const int lid = id - 4352;
    in = Wqkv; out = WqkvT; C = 3072; bx = lid % 96; by = lid / 96;
  } else {
    const int lid = id - 7424;
    in = Wout; out = WoutT; C = 1024; bx = lid & 31; by = lid >> 5;
  }
  const int R = 1024;
  const int c0 = bx * 32, r0 = by * 32;
  const int tx = threadIdx.x & 31, ty = threadIdx.x >> 5;  // ty 0..7
  #pragma unroll
  for (int i = ty; i < 32; i += 8)
    tile[i][tx] = __float2bfloat16(in[(size_t)(r0 + i) * C + (c0 + tx)]);
  __syncthreads();
  #pragma unroll
  for (int i = ty; i < 32; i += 8)
    out[(size_t)(c0 + i) * R + (r0 + tx)] = tile[tx][i];
}

// ---------------------------------------------------------------------------
// gemm_bt: C (MxN, OutT) = A (MxK, row-major bf16) @ Bt^T  (Bt is NxK bf16)
// r6/r12 measured-optimum 2-barrier structure (r22 256^2 ring reverted:
// grid 192 < 256 CUs + 1 block/CU -> 46us vs 40 here).
// gemm1: <bf16,128,128> (768 blocks); gemm2: <float,128,64> (512 blocks).
// ---------------------------------------------------------------------------
template <typename OutT, int BM, int BN>
__global__ __launch_bounds__(256) void gemm_bt(
    const __hip_bfloat16* __restrict__ A,
    const __hip_bfloat16* __restrict__ Bt,
    OutT* __restrict__ C,
    int M, int N, int K) {
  __shared__ __hip_bfloat16 lA[BM][64];
  __shared__ __hip_bfloat16 lB[BN][64];
  constexpr int NI = BM / 32, NJ = BN / 32;
  const int t = threadIdx.x;
  const int lane = t & 63, wave = t >> 6;
  const int quad = lane >> 4, ln = lane & 15;
  const int m0 = blockIdx.y * BM, n0 = blockIdx.x * BN;
  const int wm = (wave >> 1) * (BM / 2), wn = (wave & 1) * (BN / 2);
  const int srow = lane >> 3;
  const int schunk = ((lane & 7) ^ srow) * 8;

  float4v acc[NI][NJ];
  #pragma unroll
  for (int i = 0; i < NI; ++i)
    #pragma unroll
    for (int j = 0; j < NJ; ++j)
      acc[i][j] = (float4v){0.f, 0.f, 0.f, 0.f};

  for (int kt = 0; kt < K; kt += 64) {
    __syncthreads();
    #pragma unroll
    for (int g = 0; g < BM / 32; ++g) {
      const int rbase = wave * (BM / 4) + g * 8;
      __builtin_amdgcn_global_load_lds(
          (const __attribute__((address_space(1))) void*)
              (A + (size_t)(m0 + rbase + srow) * K + kt + schunk),
          (__attribute__((address_space(3))) void*)&lA[rbase][0], 16, 0, 0);
    }
    #pragma unroll
    for (int g = 0; g < BN / 32; ++g) {
      const int rbase = wave * (BN / 4) + g * 8;
      __builtin_amdgcn_global_load_lds(
          (const __attribute__((address_space(1))) void*)
              (Bt + (size_t)(n0 + rbase + srow) * K + kt + schunk),
          (__attribute__((address_space(3))) void*)&lB[rbase][0], 16, 0, 0);
    }
    __syncthreads();
    #pragma unroll
    for (int step = 0; step < 2; ++step) {
      short8 af[NI], bf[NJ];
      #pragma unroll
      for (int i = 0; i < NI; ++i)
        af[i] = *(const short8*)&lA[wm + i * 16 + ln][((step * 4 + quad) ^ (ln & 7)) * 8];
      #pragma unroll
      for (int j = 0; j < NJ; ++j)
        bf[j] = *(const short8*)&lB[wn + j * 16 + ln][((step * 4 + quad) ^ (ln & 7)) * 8];
      #pragma unroll
      for (int i = 0; i < NI; ++i)
        #pragma unroll
        for (int j = 0; j < NJ; ++j)
          acc[i][j] = __builtin_amdgcn_mfma_f32_16x16x32_bf16(af[i], bf[j], acc[i][j], 0, 0, 0);
    }
  }
  #pragma unroll
  for (int i = 0; i < NI; ++i)
    #pragma unroll
    for (int j = 0; j < NJ; ++j)
      #pragma unroll
      for (int r = 0; r < 4; ++r) {
        const int row = m0 + wm + i * 16 + quad * 4 + r;
        const int col = n0 + wn + j * 16 + ln;
        if constexpr (__is_same(OutT, float))
          C[(size_t)row * N + col] = acc[i][j][r];
        else
          C[(size_t)row * N + col] = __float2bfloat16(acc[i][j][r]);
      }
}

// ---------------------------------------------------------------------------
// Fused QKV prep (table-driven, r12 form): rope(Q,K) reshape + V transpose,
// one qkv pass, zero transcendentals. Q scaled by (1/8)*log2(e).
// ---------------------------------------------------------------------------
__global__ __launch_bounds__(256) void qkv_prep(
    const __hip_bfloat16* __restrict__ qkv,
    const float2* __restrict__ tab,
    __hip_bfloat16* __restrict__ Q,
    __hip_bfloat16* __restrict__ K,
    __hip_bfloat16* __restrict__ Vt) {
  __shared__ __hip_bfloat16 tile[64][65];
  const int s0 = blockIdx.x * 64;
  const int bh = blockIdx.y;
  const int h = bh & 15, b = bh >> 4;
  const int t = threadIdx.x;

  const int pr = t & 31, sl = t >> 5;
  const int d0 = pr * 2;
  const float qs = 0.125f * 1.44269504088896340736f;  // (1/8)*log2(e)
  #pragma unroll
  for (int ss = sl; ss < 64; ss += 8) {
    const int s = s0 + ss;
    const float2 cssn = tab[(size_t)s * 32 + pr];
    const float cs = cssn.x, sn = cssn.y;
    const size_t in_base = (size_t)(b * 2048 + s) * 3072;
    const size_t o = ((size_t)bh * 2048 + s) * 64 + d0;

    __hip_bfloat162 q2 = *(const __hip_bfloat162*)&qkv[in_base + h * 64 + d0];
    float x1 = __bfloat162float(q2.x), x2 = __bfloat162float(q2.y);
    __hip_bfloat162 qo;
    qo.x = __float2bfloat16((x1 * cs - x2 * sn) * qs);
    qo.y = __float2bfloat16((x1 * sn + x2 * cs) * qs);
    *(__hip_bfloat162*)&Q[o] = qo;

    __hip_bfloat162 k2 = *(const __hip_bfloat162*)&qkv[in_base + 1024 + h * 64 + d0];
    x1 = __bfloat162float(k2.x); x2 = __bfloat162float(k2.y);
    __hip_bfloat162 ko;
    ko.x = __float2bfloat16(x1 * cs - x2 * sn);
    ko.y = __float2bfloat16(x1 * sn + x2 * cs);
    *(__hip_bfloat162*)&K[o] = ko;
  }

  const int tx = t & 63, ty = t >> 6;  // ty 0..3
  #pragma unroll
  for (int i = ty; i < 64; i += 4)
    tile[i][tx] = qkv[(size_t)(b * 2048 + s0 + i) * 3072 + 2048 + h * 64 + tx];
  __syncthreads();
  #pragma unroll
  for (int i = ty; i < 64; i += 4)
    Vt[((size_t)bh * 64 + i) * 2048 + s0 + tx] = tile[tx][i];
}

// ---------------------------------------------------------------------------
// Flash-style causal attention — r24: r21 structure (4 waves, 64-q blocks —
// measured-best; r23's 8-wave sharing regressed) + lK SWIZZLE FIX.
// r23 counters exposed SQ_LDS_BANK_CONFLICT=3.18M (was 540K pre-sigma):
// the sigma krow permutation reads chunk (step*4+quad)^(krow&7) where
// krow&7 = (ln&3)|((nt&1)<<2) — bit2 constant per instr, ln>>2 absent ->
// only 4 bank-groups for 64 lanes = 16-way conflict on every kf b128 read.
// Fix: storage swizzle f(row) = (row&7) ^ (((row>>3)&1)<<2), applied BOTH
// at staging (source chunk ^= g2<<2) and at read (k7 ^= ((krow>>3)&1)<<2).
// Now read chunks spread 8 groups x 8 lanes (wave64-b128 floor). V layout
// was already even — unchanged. Epilogue lO writes packed to ds_write_b64
// (r-values are contiguous cols) — 4x fewer conflict events, once/block.
// ---------------------------------------------------------------------------
__global__ __launch_bounds__(256) void attention(
    const __hip_bfloat16* __restrict__ Q,
    const __hip_bfloat16* __restrict__ K,
    const __hip_bfloat16* __restrict__ Vt,
    __hip_bfloat16* __restrict__ attn) {
  __shared__ __hip_bfloat16 lK[2][64][64];    // [buf][sk][d]  f-swizzled, dbuf
  __shared__ __hip_bfloat16 lV[2][64][64];    // [buf][d][sk]  XOR-swizzled, dbuf
  __shared__ __hip_bfloat16 lO[4][16][64];    // per-wave epilogue transpose
  const int t = threadIdx.x;
  const int lane = t & 63, w = t >> 6;
  const int quad = lane >> 4, ln = lane & 15;
  const int id = blockIdx.x;
  const int bh = id & 31;                     // fast index -> XCD spread
  const int j = id >> 5;                      // 0..31
  const int k2 = j >> 3, g = j & 7;
  const int qt = 8 * k2 + ((k2 & 1) ? (7 - g) : g);   // balanced qt perm
  const int q0 = qt * 64;
  const size_t base = (size_t)bh * 2048 * 64;
  const __hip_bfloat16* Qb = Q + base;
  const __hip_bfloat16* Kb = K + base;
  const __hip_bfloat16* Vb = Vt + base;
  const int b = bh >> 4, h = bh & 15;

  const int srow = lane >> 3;
  const int schunkV = ((lane & 7) ^ srow) * 8;            // V: f(r) = r&7
  const int rb0 = w * 16;
  // sigma row base: sigma(nt, ln) = sig_base + ((nt&1)<<2) + ((nt>>1)<<5)
  const int sig_base = (ln >> 2) * 8 + (ln & 3);

  // Prologue: stage K[0] + V[0] into buf 0.
  #pragma unroll
  for (int g2 = 0; g2 < 2; ++g2) {
    const int rbase = rb0 + g2 * 8;
    const int schunkK = (((lane & 7) ^ srow) ^ (g2 << 2)) * 8;  // f-bit2 = g2
    __builtin_amdgcn_global_load_lds(
        (const __attribute__((address_space(1))) void*)
            (Kb + (size_t)(rbase + srow) * 64 + schunkK),
        (__attribute__((address_space(3))) void*)&lK[0][rbase][0], 16, 0, 0);
    __builtin_amdgcn_global_load_lds(
        (const __attribute__((address_space(1))) void*)
            (Vb + (size_t)(rbase + srow) * 2048 + schunkV),
        (__attribute__((address_space(3))) void*)&lV[0][rbase][0], 16, 0, 0);
  }

  short8 qf[2];
  {
    const size_t qrow = (size_t)(q0 + w * 16 + ln) * 64;
    qf[0] = *(const short8*)(Qb + qrow + quad * 8);
    qf[1] = *(const short8*)(Qb + qrow + 32 + quad * 8);
  }

  float4v acc_o[4];
  #pragma unroll
  for (int dt = 0; dt < 4; ++dt) acc_o[dt] = (float4v){0.f, 0.f, 0.f, 0.f};
  float suml = 0.f;

  for (int kt = 0; kt <= qt; ++kt) {
    const int buf = kt & 1;
    __syncthreads();   // drains K[kt]/V[kt] DMA (issued a full iter ago);
                       // prev iter's buf^1 reads are all before this point

    if (kt < qt) {
      #pragma unroll
      for (int g2 = 0; g2 < 2; ++g2) {
        const int rbase = rb0 + g2 * 8;
        const int schunkK = (((lane & 7) ^ srow) ^ (g2 << 2)) * 8;
        __builtin_amdgcn_global_load_lds(
            (const __attribute__((address_space(1))) void*)
                (Kb + (size_t)((kt + 1) * 64 + rbase + srow) * 64 + schunkK),
            (__attribute__((address_space(3))) void*)&lK[buf ^ 1][rbase][0], 16, 0, 0);
        __builtin_amdgcn_global_load_lds(
            (const __attribute__((address_space(1))) void*)
                (Vb + (size_t)(rbase + srow) * 2048 + (kt + 1) * 64 + schunkV),
            (__attribute__((address_space(3))) void*)&lV[buf ^ 1][rbase][0], 16, 0, 0);
      }
    }

    // QK^T swapped: s4[nt] lane(quad,ln) reg r = P[sigma(nt,quad*4+r)][q=ln]
    float4v s4[4];
    #pragma unroll
    for (int nt = 0; nt < 4; ++nt) {
      const int krow = sig_base + ((nt & 1) << 2) + ((nt >> 1) << 5);
      const int k7 = (krow & 7) ^ (((krow >> 3) & 1) << 2);   // f(krow)
      float4v a = (float4v){0.f, 0.f, 0.f, 0.f};
      #pragma unroll
      for (int step = 0; step < 2; ++step) {
        short8 kf = *(const short8*)&lK[buf][krow][((step * 4 + quad) ^ k7) * 8];
        a = __builtin_amdgcn_mfma_f32_16x16x32_bf16(kf, qf[step], a, 0, 0, 0);
      }
      s4[nt] = a;
    }
    if (kt == qt) {
      const int qr = q0 + w * 16 + ln;
      #pragma unroll
      for (int nt = 0; nt < 4; ++nt)
        #pragma unroll
        for (int r = 0; r < 4; ++r) {
          const int kglob = kt * 64 + quad * 8 + ((nt & 1) << 2) + r + ((nt >> 1) << 5);
          if (kglob > qr) s4[nt][r] = -64.f;
        }
    }
    // exp (bare v_exp_f32) + row-sum contribution
    #pragma unroll
    for (int nt = 0; nt < 4; ++nt)
      #pragma unroll
      for (int r = 0; r < 4; ++r) {
        s4[nt][r] = __builtin_amdgcn_exp2f(s4[nt][r]);
        suml += s4[nt][r];
      }
    // PV: B-frag step s = lane-local pack of s4[2s][0..3], s4[2s+1][0..3]
    #pragma unroll
    for (int s = 0; s < 2; ++s) {
      union { short8 v; short e[8]; } pb;
      #pragma unroll
      for (int i = 0; i < 4; ++i) {
        __hip_bfloat16 b0 = __float2bfloat16(s4[2 * s][i]);
        __hip_bfloat16 b1 = __float2bfloat16(s4[2 * s + 1][i]);
        pb.e[i] = *reinterpret_cast<short*>(&b0);
        pb.e[4 + i] = *reinterpret_cast<short*>(&b1);
      }
      #pragma unroll
      for (int dt = 0; dt < 4; ++dt) {
        short8 vf = *(const short8*)&lV[buf][dt * 16 + ln][((s * 4 + quad) ^ (ln & 7)) * 8];
        acc_o[dt] = __builtin_amdgcn_mfma_f32_16x16x32_bf16(vf, pb.v, acc_o[dt], 0, 0, 0);
      }
    }
  }

  // l[q] = sum over the 4 quads holding q=ln's P-columns
  float l0 = suml + __shfl_xor(suml, 16);
  const float inv = 1.0f / (l0 + __shfl_xor(l0, 32));

  // Epilogue: lane holds O^T[d=dt*16+quad*4+r][q=ln]; transpose via per-wave
  // LDS tile; packed 8B writes (r-values contiguous in lO's col dim).
  #pragma unroll
  for (int dt = 0; dt < 4; ++dt) {
    union { uint2 u; short e[4]; } pk;
    #pragma unroll
    for (int r = 0; r < 4; ++r) {
      __hip_bfloat16 bv = __float2bfloat16(acc_o[dt][r] * inv);
      pk.e[r] = *reinterpret_cast<short*>(&bv);
    }
    *(uint2*)&lO[w][ln][dt * 16 + quad * 4] = pk.u;
  }

  const int orow = lane >> 2;           // q' 0..15
  const int od = (lane & 3) * 16;       // d base (16 elems = 32B per lane)
  const uint4 w0 = *(const uint4*)&lO[w][orow][od];
  const uint4 w1 = *(const uint4*)&lO[w][orow][od + 8];
  const size_t rg = (size_t)(b * 2048 + q0 + w * 16 + orow);
  *(uint4*)&attn[rg * 1024 + h * 64 + od] = w0;
  *(uint4*)&attn[rg * 1024 + h * 64 + od + 8] = w1;
}

// ---------------------------------------------------------------------------
extern "C" void kernel_launch(void* const* d_in, const int* in_sizes, int n_in,
                              void* d_out, int out_size, void* d_ws, size_t ws_size,
                              hipStream_t stream) {
  const float* x    = (const float*)d_in[0];  // (2,2048,1024) fp32
  const float* Wqkv = (const float*)d_in[1];  // (1024,3072)   fp32
  const float* Wout = (const float*)d_in[2];  // (1024,1024)   fp32
  float* out = (float*)d_out;                 // (2,2048,1024) fp32

  __hip_bfloat16* ws = (__hip_bfloat16*)d_ws;
  __hip_bfloat16* xb    = ws;                          // 4096*1024
  __hip_bfloat16* WqkvT = xb    + (size_t)4096 * 1024; // 3072*1024
  __hip_bfloat16* WoutT = WqkvT + (size_t)3072 * 1024; // 1024*1024
  __hip_bfloat16* qkv   = WoutT + (size_t)1024 * 1024; // 4096*3072
  __hip_bfloat16* Q     = qkv   + (size_t)4096 * 3072; // 32*2048*64
  __hip_bfloat16* K     = Q     + (size_t)32 * 2048 * 64;
  __hip_bfloat16* Vt    = K     + (size_t)32 * 2048 * 64;
  __hip_bfloat16* attn  = Vt    + (size_t)32 * 2048 * 64;  // dedicated
  float2*         tab   = (float2*)(attn + (size_t)4096 * 1024);  // 2048x32

  prep_all<<<8448, 256, 0, stream>>>(x, xb, tab, Wqkv, Wout, WqkvT, WoutT);
  gemm_bt<__hip_bfloat16, 128, 128><<<dim3(3072 / 128, 4096 / 128), 256, 0, stream>>>(xb, WqkvT, qkv, 4096, 3072, 1024);
  qkv_prep<<<dim3(32, 32), 256, 0, stream>>>(qkv, tab, Q, K, Vt);
  attention<<<1024, 256, 0, stream>>>(Q, K, Vt, attn);
  gemm_bt<float, 128, 64><<<dim3(1024 / 64, 4096 / 128), 256, 0, stream>>>(attn, WoutT, out, 4096, 1024, 1024);
}

// Round 10
// 170.180 us; speedup vs baseline: 1.0871x; 1.0114x over previous
//
#include <hip/hip_runtime.h>
#include <hip/hip_bf16.h>

typedef __attribute__((ext_vector_type(8))) short short8;     // 8 bf16 (MFMA A/B frag, K=32)
typedef __attribute__((ext_vector_type(4))) float float4v;    // MFMA C/D frag

// RoPE on an 8-elem bf16 chunk (4 pairs). tA/tB = tab[p..p+1], tab[p+2..p+3]
// as (cos,sin,cos,sin). Identical rounding chain to the old qkv_prep path.
__device__ inline short8 rope8(short8 raw, float4 tA, float4 tB, float scale) {
  float c[4] = {tA.x, tA.z, tB.x, tB.z};
  float s[4] = {tA.y, tA.w, tB.y, tB.w};
  union { short8 v; short e[8]; } in, out;
  in.v = raw;
  #pragma unroll
  for (int j = 0; j < 4; ++j) {
    __hip_bfloat16 h1 = *reinterpret_cast<__hip_bfloat16*>(&in.e[2 * j]);
    __hip_bfloat16 h2 = *reinterpret_cast<__hip_bfloat16*>(&in.e[2 * j + 1]);
    const float x1 = __bfloat162float(h1), x2 = __bfloat162float(h2);
    __hip_bfloat16 o1 = __float2bfloat16((x1 * c[j] - x2 * s[j]) * scale);
    __hip_bfloat16 o2 = __float2bfloat16((x1 * s[j] + x2 * c[j]) * scale);
    out.e[2 * j]     = *reinterpret_cast<short*>(&o1);
    out.e[2 * j + 1] = *reinterpret_cast<short*>(&o2);
  }
  return out.v;
}

// ---------------------------------------------------------------------------
// prep_all: all input prep in ONE launch.
//   blocks [0,4096):     x fp32 -> xb bf16 (float4 vectorized)
//   blocks [4096,4352):  RoPE table tab[s][p] = (cos,sin), 512 KB, L2-resident
//   blocks [4352,7424):  Wqkv (1024x3072) -> WqkvT (3072x1024) bf16 transpose
//   blocks [7424,8448):  Wout (1024x1024) -> WoutT transpose
// r25: transpose STORE phase packs 2 rows/lane -> 4B stores (was 2B/lane).
// ---------------------------------------------------------------------------
__global__ __launch_bounds__(256) void prep_all(
    const float* __restrict__ x, __hip_bfloat16* __restrict__ xb,
    float2* __restrict__ tab,
    const float* __restrict__ Wqkv, const float* __restrict__ Wout,
    __hip_bfloat16* __restrict__ WqkvT, __hip_bfloat16* __restrict__ WoutT) {
  __shared__ __hip_bfloat16 tile[32][33];
  const int id = blockIdx.x;
  if (id < 4096) {
    const int i = id * 256 + threadIdx.x;
    const float4 v = *(const float4*)(x + (size_t)i * 4);
    __hip_bfloat16 o[4];
    o[0] = __float2bfloat16(v.x); o[1] = __float2bfloat16(v.y);
    o[2] = __float2bfloat16(v.z); o[3] = __float2bfloat16(v.w);
    *(uint2*)(xb + (size_t)i * 4) = *(const uint2*)o;
    return;
  }
  if (id < 4352) {
    const int i = (id - 4096) * 256 + threadIdx.x;   // 65536
    const int s = i >> 5, p = i & 31;
    const float freq = powf(10000.f, -(float)(p * 2) / 64.f);
    float sn, cs;
    sincosf((float)s * freq, &sn, &cs);
    tab[i] = make_float2(cs, sn);
    return;
  }
  const float* in;
  __hip_bfloat16* out;
  int C, bx, by;
  if (id < 7424) {
    const int lid = id - 4352;
    in = Wqkv; out = WqkvT; C = 3072; bx = lid % 96; by = lid / 96;
  } else {
    const int lid = id - 7424;
    in = Wout; out = WoutT; C = 1024; bx = lid & 31; by = lid >> 5;
  }
  const int R = 1024;
  const int c0 = bx * 32, r0 = by * 32;
  const int tx = threadIdx.x & 31, ty = threadIdx.x >> 5;  // ty 0..7
  #pragma unroll
  for (int i = ty; i < 32; i += 8)
    tile[i][tx] = __float2bfloat16(in[(size_t)(r0 + i) * C + (c0 + tx)]);
  __syncthreads();
  // packed store: lane owns row-pair (2sx, 2sx+1) at col i -> one 4B store
  const int sx = threadIdx.x & 15, sy = threadIdx.x >> 4;  // sy 0..15
  #pragma unroll
  for (int i = sy; i < 32; i += 16) {
    union { unsigned u; short e[2]; } pk;
    pk.e[0] = *reinterpret_cast<short*>(&tile[2 * sx][i]);
    pk.e[1] = *reinterpret_cast<short*>(&tile[2 * sx + 1][i]);
    *(unsigned*)&out[(size_t)(c0 + i) * R + r0 + 2 * sx] = pk.u;
  }
}

// ---------------------------------------------------------------------------
// gemm_bt: C (MxN, OutT) = A (MxK, row-major bf16) @ Bt^T  (Bt is NxK bf16)
// r6/r12 measured-optimum 2-barrier structure (r22 256^2 ring reverted:
// grid 192 < 256 CUs + 1 block/CU -> 46us vs 40 here).
// gemm1: <bf16,128,128> (768 blocks); gemm2: <float,128,64> (512 blocks).
// ---------------------------------------------------------------------------
template <typename OutT, int BM, int BN>
__global__ __launch_bounds__(256) void gemm_bt(
    const __hip_bfloat16* __restrict__ A,
    const __hip_bfloat16* __restrict__ Bt,
    OutT* __restrict__ C,
    int M, int N, int K) {
  __shared__ __hip_bfloat16 lA[BM][64];
  __shared__ __hip_bfloat16 lB[BN][64];
  constexpr int NI = BM / 32, NJ = BN / 32;
  const int t = threadIdx.x;
  const int lane = t & 63, wave = t >> 6;
  const int quad = lane >> 4, ln = lane & 15;
  const int m0 = blockIdx.y * BM, n0 = blockIdx.x * BN;
  const int wm = (wave >> 1) * (BM / 2), wn = (wave & 1) * (BN / 2);
  const int srow = lane >> 3;
  const int schunk = ((lane & 7) ^ srow) * 8;

  float4v acc[NI][NJ];
  #pragma unroll
  for (int i = 0; i < NI; ++i)
    #pragma unroll
    for (int j = 0; j < NJ; ++j)
      acc[i][j] = (float4v){0.f, 0.f, 0.f, 0.f};

  for (int kt = 0; kt < K; kt += 64) {
    __syncthreads();
    #pragma unroll
    for (int g = 0; g < BM / 32; ++g) {
      const int rbase = wave * (BM / 4) + g * 8;
      __builtin_amdgcn_global_load_lds(
          (const __attribute__((address_space(1))) void*)
              (A + (size_t)(m0 + rbase + srow) * K + kt + schunk),
          (__attribute__((address_space(3))) void*)&lA[rbase][0], 16, 0, 0);
    }
    #pragma unroll
    for (int g = 0; g < BN / 32; ++g) {
      const int rbase = wave * (BN / 4) + g * 8;
      __builtin_amdgcn_global_load_lds(
          (const __attribute__((address_space(1))) void*)
              (Bt + (size_t)(n0 + rbase + srow) * K + kt + schunk),
          (__attribute__((address_space(3))) void*)&lB[rbase][0], 16, 0, 0);
    }
    __syncthreads();
    #pragma unroll
    for (int step = 0; step < 2; ++step) {
      short8 af[NI], bf[NJ];
      #pragma unroll
      for (int i = 0; i < NI; ++i)
        af[i] = *(const short8*)&lA[wm + i * 16 + ln][((step * 4 + quad) ^ (ln & 7)) * 8];
      #pragma unroll
      for (int j = 0; j < NJ; ++j)
        bf[j] = *(const short8*)&lB[wn + j * 16 + ln][((step * 4 + quad) ^ (ln & 7)) * 8];
      #pragma unroll
      for (int i = 0; i < NI; ++i)
        #pragma unroll
        for (int j = 0; j < NJ; ++j)
          acc[i][j] = __builtin_amdgcn_mfma_f32_16x16x32_bf16(af[i], bf[j], acc[i][j], 0, 0, 0);
    }
  }
  #pragma unroll
  for (int i = 0; i < NI; ++i)
    #pragma unroll
    for (int j = 0; j < NJ; ++j)
      #pragma unroll
      for (int r = 0; r < 4; ++r) {
        const int row = m0 + wm + i * 16 + quad * 4 + r;
        const int col = n0 + wn + j * 16 + ln;
        if constexpr (__is_same(OutT, float))
          C[(size_t)row * N + col] = acc[i][j][r];
        else
          C[(size_t)row * N + col] = __float2bfloat16(acc[i][j][r]);
      }
}

// ---------------------------------------------------------------------------
// qkv_prep r25: K RoPE (vectorized 16B) + V transpose (8B both sides).
// Q DROPPED — attention fuses RoPE-Q into its one-time qf load (Q made a
// pointless 4MB-write + 4MB-read HBM round-trip; rounding chain identical).
// ---------------------------------------------------------------------------
__global__ __launch_bounds__(256) void qkv_prep(
    const __hip_bfloat16* __restrict__ qkv,
    const float2* __restrict__ tab,
    __hip_bfloat16* __restrict__ K,
    __hip_bfloat16* __restrict__ Vt) {
  __shared__ __hip_bfloat16 tile[64][68];     // +4 pad: 8B-aligned rows
  const int s0 = blockIdx.x * 64;
  const int bh = blockIdx.y;
  const int h = bh & 15, b = bh >> 4;
  const int t = threadIdx.x;

  // ---- K RoPE: thread covers 8 d (16B); 8 thr/row, 32 rows/pass, 2 passes.
  const int dd = (t & 7) * 8;
  const int sl = t >> 3;                      // 0..31
  #pragma unroll
  for (int ss = sl; ss < 64; ss += 32) {
    const int s = s0 + ss;
    short8 kv = *(const short8*)&qkv[(size_t)(b * 2048 + s) * 3072 + 1024 + h * 64 + dd];
    const float4 tA = *(const float4*)&tab[(size_t)s * 32 + (dd >> 1)];
    const float4 tB = *(const float4*)&tab[(size_t)s * 32 + (dd >> 1) + 2];
    *(short8*)&K[((size_t)bh * 2048 + s) * 64 + dd] = rope8(kv, tA, tB, 1.0f);
  }

  // ---- V transpose: 8B loads (4 d/lane), 8B stores (4 s/lane).
  const int dgrp = (t & 15) * 4;              // d base for load
  const int srow = t >> 4;                    // 0..15
  #pragma unroll
  for (int i = srow; i < 64; i += 16) {
    ushort4 v4 = *(const ushort4*)&qkv[(size_t)(b * 2048 + s0 + i) * 3072 + 2048 + h * 64 + dgrp];
    *(ushort4*)&tile[i][dgrp] = v4;
  }
  __syncthreads();
  const int vx = t & 15, vy = t >> 4;         // vx -> s-quad, vy -> d
  #pragma unroll
  for (int d = vy; d < 64; d += 16) {
    union { ushort4 v; short e[4]; } pk;
    #pragma unroll
    for (int jj = 0; jj < 4; ++jj)
      pk.e[jj] = *reinterpret_cast<short*>(&tile[4 * vx + jj][d]);
    *(ushort4*)&Vt[((size_t)bh * 64 + d) * 2048 + s0 + 4 * vx] = pk.v;
  }
}

// ---------------------------------------------------------------------------
// Flash-style causal attention — r25: r24 form (swapped-operand QK,
// in-register P, fixed f-swizzle lK, packed lO epilogue) + FUSED RoPE-Q:
// qf is built from the raw qkv q-region + tab (one-time, ~50 VALU ops at
// 25%-busy VALU — free); Q buffer no longer exists.
// ---------------------------------------------------------------------------
__global__ __launch_bounds__(256) void attention(
    const __hip_bfloat16* __restrict__ qkv,
    const float2* __restrict__ tab,
    const __hip_bfloat16* __restrict__ K,
    const __hip_bfloat16* __restrict__ Vt,
    __hip_bfloat16* __restrict__ attn) {
  __shared__ __hip_bfloat16 lK[2][64][64];    // [buf][sk][d]  f-swizzled, dbuf
  __shared__ __hip_bfloat16 lV[2][64][64];    // [buf][d][sk]  XOR-swizzled, dbuf
  __shared__ __hip_bfloat16 lO[4][16][64];    // per-wave epilogue transpose
  const int t = threadIdx.x;
  const int lane = t & 63, w = t >> 6;
  const int quad = lane >> 4, ln = lane & 15;
  const int id = blockIdx.x;
  const int bh = id & 31;                     // fast index -> XCD spread
  const int j = id >> 5;                      // 0..31
  const int k2 = j >> 3, g = j & 7;
  const int qt = 8 * k2 + ((k2 & 1) ? (7 - g) : g);   // balanced qt perm
  const int q0 = qt * 64;
  const size_t base = (size_t)bh * 2048 * 64;
  const __hip_bfloat16* Kb = K + base;
  const __hip_bfloat16* Vb = Vt + base;
  const int b = bh >> 4, h = bh & 15;

  const int srow = lane >> 3;
  const int schunkV = ((lane & 7) ^ srow) * 8;            // V: f(r) = r&7
  const int rb0 = w * 16;
  // sigma row base: sigma(nt, ln) = sig_base + ((nt&1)<<2) + ((nt>>1)<<5)
  const int sig_base = (ln >> 2) * 8 + (ln & 3);

  // Prologue: stage K[0] + V[0] into buf 0.
  #pragma unroll
  for (int g2 = 0; g2 < 2; ++g2) {
    const int rbase = rb0 + g2 * 8;
    const int schunkK = (((lane & 7) ^ srow) ^ (g2 << 2)) * 8;  // f-bit2 = g2
    __builtin_amdgcn_global_load_lds(
        (const __attribute__((address_space(1))) void*)
            (Kb + (size_t)(rbase + srow) * 64 + schunkK),
        (__attribute__((address_space(3))) void*)&lK[0][rbase][0], 16, 0, 0);
    __builtin_amdgcn_global_load_lds(
        (const __attribute__((address_space(1))) void*)
            (Vb + (size_t)(rbase + srow) * 2048 + schunkV),
        (__attribute__((address_space(3))) void*)&lV[0][rbase][0], 16, 0, 0);
  }

  // qf: raw qkv q-slice + fused RoPE (scale = (1/8)*log2(e) for exp2-softmax)
  short8 qf[2];
  {
    const float qs = 0.125f * 1.44269504088896340736f;
    const int s = q0 + w * 16 + ln;
    const size_t qrow = (size_t)(b * 2048 + s) * 3072 + h * 64;
    short8 raw0 = *(const short8*)&qkv[qrow + quad * 8];
    short8 raw1 = *(const short8*)&qkv[qrow + 32 + quad * 8];
    const float4 ta = *(const float4*)&tab[(size_t)s * 32 + quad * 4];
    const float4 tb = *(const float4*)&tab[(size_t)s * 32 + quad * 4 + 2];
    const float4 tc = *(const float4*)&tab[(size_t)s * 32 + 16 + quad * 4];
    const float4 td = *(const float4*)&tab[(size_t)s * 32 + 16 + quad * 4 + 2];
    qf[0] = rope8(raw0, ta, tb, qs);
    qf[1] = rope8(raw1, tc, td, qs);
  }

  float4v acc_o[4];
  #pragma unroll
  for (int dt = 0; dt < 4; ++dt) acc_o[dt] = (float4v){0.f, 0.f, 0.f, 0.f};
  float suml = 0.f;

  for (int kt = 0; kt <= qt; ++kt) {
    const int buf = kt & 1;
    __syncthreads();   // drains K[kt]/V[kt] DMA (issued a full iter ago);
                       // prev iter's buf^1 reads are all before this point

    if (kt < qt) {
      #pragma unroll
      for (int g2 = 0; g2 < 2; ++g2) {
        const int rbase = rb0 + g2 * 8;
        const int schunkK = (((lane & 7) ^ srow) ^ (g2 << 2)) * 8;
        __builtin_amdgcn_global_load_lds(
            (const __attribute__((address_space(1))) void*)
                (Kb + (size_t)((kt + 1) * 64 + rbase + srow) * 64 + schunkK),
            (__attribute__((address_space(3))) void*)&lK[buf ^ 1][rbase][0], 16, 0, 0);
        __builtin_amdgcn_global_load_lds(
            (const __attribute__((address_space(1))) void*)
                (Vb + (size_t)(rbase + srow) * 2048 + (kt + 1) * 64 + schunkV),
            (__attribute__((address_space(3))) void*)&lV[buf ^ 1][rbase][0], 16, 0, 0);
      }
    }

    // QK^T swapped: s4[nt] lane(quad,ln) reg r = P[sigma(nt,quad*4+r)][q=ln]
    float4v s4[4];
    #pragma unroll
    for (int nt = 0; nt < 4; ++nt) {
      const int krow = sig_base + ((nt & 1) << 2) + ((nt >> 1) << 5);
      const int k7 = (krow & 7) ^ (((krow >> 3) & 1) << 2);   // f(krow)
      float4v a = (float4v){0.f, 0.f, 0.f, 0.f};
      #pragma unroll
      for (int step = 0; step < 2; ++step) {
        short8 kf = *(const short8*)&lK[buf][krow][((step * 4 + quad) ^ k7) * 8];
        a = __builtin_amdgcn_mfma_f32_16x16x32_bf16(kf, qf[step], a, 0, 0, 0);
      }
      s4[nt] = a;
    }
    if (kt == qt) {
      const int qr = q0 + w * 16 + ln;
      #pragma unroll
      for (int nt = 0; nt < 4; ++nt)
        #pragma unroll
        for (int r = 0; r < 4; ++r) {
          const int kglob = kt * 64 + quad * 8 + ((nt & 1) << 2) + r + ((nt >> 1) << 5);
          if (kglob > qr) s4[nt][r] = -64.f;
        }
    }
    // exp (bare v_exp_f32) + row-sum contribution
    #pragma unroll
    for (int nt = 0; nt < 4; ++nt)
      #pragma unroll
      for (int r = 0; r < 4; ++r) {
        s4[nt][r] = __builtin_amdgcn_exp2f(s4[nt][r]);
        suml += s4[nt][r];
      }
    // PV: B-frag step s = lane-local pack of s4[2s][0..3], s4[2s+1][0..3]
    #pragma unroll
    for (int s = 0; s < 2; ++s) {
      union { short8 v; short e[8]; } pb;
      #pragma unroll
      for (int i = 0; i < 4; ++i) {
        __hip_bfloat16 b0 = __float2bfloat16(s4[2 * s][i]);
        __hip_bfloat16 b1 = __float2bfloat16(s4[2 * s + 1][i]);
        pb.e[i] = *reinterpret_cast<short*>(&b0);
        pb.e[4 + i] = *reinterpret_cast<short*>(&b1);
      }
      #pragma unroll
      for (int dt = 0; dt < 4; ++dt) {
        short8 vf = *(const short8*)&lV[buf][dt * 16 + ln][((s * 4 + quad) ^ (ln & 7)) * 8];
        acc_o[dt] = __builtin_amdgcn_mfma_f32_16x16x32_bf16(vf, pb.v, acc_o[dt], 0, 0, 0);
      }
    }
  }

  // l[q] = sum over the 4 quads holding q=ln's P-columns
  float l0 = suml + __shfl_xor(suml, 16);
  const float inv = 1.0f / (l0 + __shfl_xor(l0, 32));

  // Epilogue: lane holds O^T[d=dt*16+quad*4+r][q=ln]; transpose via per-wave
  // LDS tile; packed 8B writes (r-values contiguous in lO's col dim).
  #pragma unroll
  for (int dt = 0; dt < 4; ++dt) {
    union { uint2 u; short e[4]; } pk;
    #pragma unroll
    for (int r = 0; r < 4; ++r) {
      __hip_bfloat16 bv = __float2bfloat16(acc_o[dt][r] * inv);
      pk.e[r] = *reinterpret_cast<short*>(&bv);
    }
    *(uint2*)&lO[w][ln][dt * 16 + quad * 4] = pk.u;
  }

  const int orow = lane >> 2;           // q' 0..15
  const int od = (lane & 3) * 16;       // d base (16 elems = 32B per lane)
  const uint4 w0 = *(const uint4*)&lO[w][orow][od];
  const uint4 w1 = *(const uint4*)&lO[w][orow][od + 8];
  const size_t rg = (size_t)(b * 2048 + q0 + w * 16 + orow);
  *(uint4*)&attn[rg * 1024 + h * 64 + od] = w0;
  *(uint4*)&attn[rg * 1024 + h * 64 + od + 8] = w1;
}

// ---------------------------------------------------------------------------
extern "C" void kernel_launch(void* const* d_in, const int* in_sizes, int n_in,
                              void* d_out, int out_size, void* d_ws, size_t ws_size,
                              hipStream_t stream) {
  const float* x    = (const float*)d_in[0];  // (2,2048,1024) fp32
  const float* Wqkv = (const float*)d_in[1];  // (1024,3072)   fp32
  const float* Wout = (const float*)d_in[2];  // (1024,1024)   fp32
  float* out = (float*)d_out;                 // (2,2048,1024) fp32

  __hip_bfloat16* ws = (__hip_bfloat16*)d_ws;
  __hip_bfloat16* xb    = ws;                          // 4096*1024
  __hip_bfloat16* WqkvT = xb    + (size_t)4096 * 1024; // 3072*1024
  __hip_bfloat16* WoutT = WqkvT + (size_t)3072 * 1024; // 1024*1024
  __hip_bfloat16* qkv   = WoutT + (size_t)1024 * 1024; // 4096*3072
  __hip_bfloat16* Q     = qkv   + (size_t)4096 * 3072; // slot unused (r25)
  __hip_bfloat16* K     = Q     + (size_t)32 * 2048 * 64;
  __hip_bfloat16* Vt    = K     + (size_t)32 * 2048 * 64;
  __hip_bfloat16* attn  = Vt    + (size_t)32 * 2048 * 64;  // dedicated
  float2*         tab   = (float2*)(attn + (size_t)4096 * 1024);  // 2048x32

  prep_all<<<8448, 256, 0, stream>>>(x, xb, tab, Wqkv, Wout, WqkvT, WoutT);
  gemm_bt<__hip_bfloat16, 128, 128><<<dim3(3072 / 128, 4096 / 128), 256, 0, stream>>>(xb, WqkvT, qkv, 4096, 3072, 1024);
  qkv_prep<<<dim3(32, 32), 256, 0, stream>>>(qkv, tab, K, Vt);
  attention<<<1024, 256, 0, stream>>>(qkv, tab, K, Vt, attn);
  gemm_bt<float, 128, 64><<<dim3(1024 / 64, 4096 / 128), 256, 0, stream>>>(attn, WoutT, out, 4096, 1024, 1024);
}